// Round 2
// baseline (459.228 us; speedup 1.0000x reference)
//
#include <hip/hip_runtime.h>

// CrossAttentionModel on MI355X (gfx950) — round 2.
//
// Math (softmax row-constant invariance + sum(w)=1):
//   Mt[f][e] = sum_a Wk[f][a] Wq[e][a]   (split-bf16 3-pass, ~f32 accurate)
//   wvec[f]  = Wk bq ; cvec[e] = bv Wo + bo
//   q'[i][f] = sum_e x[i][e] Mt[f][e] + wvec[f]  (3-pass, stored fp16)
//   scores   = q' y^T   (fp16 single-pass MFMA, err ~0.012 on std-22 scores)
//   out      = (softmax(scores) y) (Wv Wo) + cvec   (fp16 value path)
// Flash: split-KV=4 across blocks (occupancy), no y LDS staging (fragments
// direct from global), per-wave P round-trip in LDS, deferred rescale.

#define DEV static __device__ __forceinline__

typedef __attribute__((ext_vector_type(8))) short s8v;        // 8 bf16
typedef __attribute__((ext_vector_type(8))) _Float16 h8v;     // 8 fp16
typedef __attribute__((ext_vector_type(4))) _Float16 h4v;
typedef __attribute__((ext_vector_type(4))) float f4v;
typedef __attribute__((ext_vector_type(4))) float float4v;
typedef __attribute__((ext_vector_type(4))) unsigned int u32x4;
typedef unsigned short u16;
typedef unsigned int u32;

constexpr int BB = 16;
constexpr int LQ = 1024;
constexpr int LK = 2048;
constexpr int E = 512;
constexpr int F = 256;
constexpr int AD = 512;

DEV u16 f2bf(float x) {
    u32 u = __builtin_bit_cast(u32, x);
    u += 0x7fff + ((u >> 16) & 1);
    return (u16)(u >> 16);
}
DEV float bf2f(u16 h) { return __builtin_bit_cast(float, (u32)h << 16); }

DEV f4v MF(s8v a, s8v b, f4v c) {
    return __builtin_amdgcn_mfma_f32_16x16x32_bf16(a, b, c, 0, 0, 0);
}
DEV f4v MF16(h8v a, h8v b, f4v c) {
    return __builtin_amdgcn_mfma_f32_16x16x32_f16(a, b, c, 0, 0, 0);
}

// ---------------------------------------------------------------------------
// wvec[f] = sum_a Wk[f][a] bq[a] ; cvec[e] = bo[e] + sum_a bv[a] Wo[a][e]
__global__ __launch_bounds__(512) void kvec_kernel(
    const float* __restrict__ Wk, const float* __restrict__ bq,
    const float* __restrict__ bv, const float* __restrict__ Wo,
    const float* __restrict__ bo, float* __restrict__ wvec,
    float* __restrict__ cvec)
{
    int t = threadIdx.x;
    if (t < F) {
        float s = 0.f;
        for (int a = 0; a < AD; ++a) s += Wk[(size_t)t * AD + a] * bq[a];
        wvec[t] = s;
    }
    float s = bo[t];
    for (int a = 0; a < AD; ++a) s += bv[a] * Wo[(size_t)a * E + t];
    cvec[t] = s;
}

// ---------------------------------------------------------------------------
// Split-bf16 NT GEMM (weights): C[m][n] = sum_k A[m][k]*B[n][k], K=512.
// MODE 0: -> split bf16 (Oh hi, Ol lo), ldc=512   [Mt: hi/lo for q' GEMM]
// MODE 2: A read transposed A[k][m]; -> fp16 bits in Oh, ldc=256  [Nt]
template <int MODE>
__global__ __launch_bounds__(256) void splitnt(
    const float* __restrict__ Ag, const float* __restrict__ Bg,
    u16* __restrict__ Oh, u16* __restrict__ Ol)
{
    constexpr int LDC = (MODE == 0) ? 512 : 256;
    __shared__ u16 Ash[64][40], Asl[64][40];
    __shared__ u16 Bsh[256][40], Bsl[256][40];

    const int tid = threadIdx.x;
    const int w = tid >> 6, lane = tid & 63;
    const int g = lane >> 4, qn = lane & 15;
    const int wr = w >> 1, wc = w & 1;
    const int m0 = blockIdx.x * 64, n0 = blockIdx.y * 256;

    f4v acc[2][8];
#pragma unroll
    for (int i = 0; i < 2; ++i)
#pragma unroll
        for (int j = 0; j < 8; ++j) acc[i][j] = (f4v){0.f, 0.f, 0.f, 0.f};

    for (int k0 = 0; k0 < 512; k0 += 32) {
        __syncthreads();
        if (MODE == 0) {
            int r = tid & 63, c = (tid >> 6) * 8;
            const float* s = Ag + (size_t)(m0 + r) * 512 + k0 + c;
            float4v v0 = *(const float4v*)s, v1 = *(const float4v*)(s + 4);
            short hh[8], ll[8];
#pragma unroll
            for (int i = 0; i < 8; ++i) {
                float x = (i < 4) ? v0[i] : v1[i - 4];
                u16 h = f2bf(x);
                hh[i] = (short)h;
                ll[i] = (short)f2bf(x - bf2f(h));
            }
            *(s8v*)&Ash[r][c] = (s8v){hh[0],hh[1],hh[2],hh[3],hh[4],hh[5],hh[6],hh[7]};
            *(s8v*)&Asl[r][c] = (s8v){ll[0],ll[1],ll[2],ll[3],ll[4],ll[5],ll[6],ll[7]};
        } else {
            int k = tid >> 3, mc = (tid & 7) * 8;
            const float* s = Ag + (size_t)(k0 + k) * 512 + m0 + mc;
            float4v v0 = *(const float4v*)s, v1 = *(const float4v*)(s + 4);
#pragma unroll
            for (int i = 0; i < 8; ++i) {
                float x = (i < 4) ? v0[i] : v1[i - 4];
                u16 h = f2bf(x);
                Ash[mc + i][k] = h;
                Asl[mc + i][k] = f2bf(x - bf2f(h));
            }
        }
        {
            const float* s = Bg + (size_t)(n0 + tid) * 512 + k0;
#pragma unroll
            for (int c = 0; c < 32; c += 8) {
                float4v v0 = *(const float4v*)(s + c), v1 = *(const float4v*)(s + c + 4);
                short hh[8], ll[8];
#pragma unroll
                for (int i = 0; i < 8; ++i) {
                    float x = (i < 4) ? v0[i] : v1[i - 4];
                    u16 h = f2bf(x);
                    hh[i] = (short)h;
                    ll[i] = (short)f2bf(x - bf2f(h));
                }
                *(s8v*)&Bsh[tid][c] = (s8v){hh[0],hh[1],hh[2],hh[3],hh[4],hh[5],hh[6],hh[7]};
                *(s8v*)&Bsl[tid][c] = (s8v){ll[0],ll[1],ll[2],ll[3],ll[4],ll[5],ll[6],ll[7]};
            }
        }
        __syncthreads();

        s8v ah[2], al[2], bh[8], bl[8];
#pragma unroll
        for (int mt = 0; mt < 2; ++mt) {
            ah[mt] = *(const s8v*)&Ash[wr * 32 + mt * 16 + qn][g * 8];
            al[mt] = *(const s8v*)&Asl[wr * 32 + mt * 16 + qn][g * 8];
        }
#pragma unroll
        for (int nt = 0; nt < 8; ++nt) {
            bh[nt] = *(const s8v*)&Bsh[wc * 128 + nt * 16 + qn][g * 8];
            bl[nt] = *(const s8v*)&Bsl[wc * 128 + nt * 16 + qn][g * 8];
        }
#pragma unroll
        for (int mt = 0; mt < 2; ++mt)
#pragma unroll
            for (int nt = 0; nt < 8; ++nt) {
                acc[mt][nt] = MF(ah[mt], bh[nt], acc[mt][nt]);
                acc[mt][nt] = MF(ah[mt], bl[nt], acc[mt][nt]);
                acc[mt][nt] = MF(al[mt], bh[nt], acc[mt][nt]);
            }
    }

#pragma unroll
    for (int mt = 0; mt < 2; ++mt)
#pragma unroll
        for (int nt = 0; nt < 8; ++nt)
#pragma unroll
            for (int r = 0; r < 4; ++r) {
                int gm = m0 + wr * 32 + mt * 16 + 4 * g + r;
                int gn = n0 + wc * 128 + nt * 16 + qn;
                float v = acc[mt][nt][r];
                if (MODE == 0) {
                    u16 h = f2bf(v);
                    Oh[(size_t)gm * LDC + gn] = h;
                    Ol[(size_t)gm * LDC + gn] = f2bf(v - bf2f(h));
                } else {
                    Oh[(size_t)gm * LDC + gn] = __builtin_bit_cast(u16, (_Float16)v);
                }
            }
}

// ---------------------------------------------------------------------------
// prep: y f32 -> y16 fp16 [B][LK][F] and yTb fp16 blocked [B][LK/32][F][32]
__global__ __launch_bounds__(256) void prep16(
    const float* __restrict__ y, _Float16* __restrict__ y16,
    _Float16* __restrict__ yTb)
{
    const int t = threadIdx.x;            // f index 0..255
    const int j0 = blockIdx.x * 64;
    const int b = blockIdx.y;
    u32 pk[32];
#pragma unroll
    for (int jj = 0; jj < 64; ++jj) {
        size_t idx = (size_t)(b * LK + j0 + jj) * F + t;
        float v = y[idx];
        _Float16 h = (_Float16)v;
        y16[idx] = h;
        u16 hb = __builtin_bit_cast(u16, h);
        if (jj & 1) pk[jj >> 1] |= (u32)hb << 16; else pk[jj >> 1] = (u32)hb;
    }
#pragma unroll
    for (int ti = 0; ti < 2; ++ti) {
        u32* dst = (u32*)(yTb + (((size_t)b * 64 + (j0 >> 5) + ti) * 256 + t) * 32);
#pragma unroll
        for (int i = 0; i < 4; ++i)
            *(u32x4*)(dst + 4 * i) =
                (u32x4){pk[ti*16 + 4*i], pk[ti*16 + 4*i+1], pk[ti*16 + 4*i+2], pk[ti*16 + 4*i+3]};
    }
}

// ---------------------------------------------------------------------------
// q'[i][f] = sum_e x[i][e] Mt[f][e] + wvec[f]  -> fp16.
// A (x) staged+split in LDS; B (Mth/Mtl, 512KB) direct from global (L2-hot).
__global__ __launch_bounds__(256) void qprime16(
    const float* __restrict__ x, const u16* __restrict__ Mth,
    const u16* __restrict__ Mtl, const float* __restrict__ wv,
    _Float16* __restrict__ q16)
{
    __shared__ u16 Ash[64][40], Asl[64][40];
    const int tid = threadIdx.x;
    const int w = tid >> 6, lane = tid & 63;
    const int g = lane >> 4, qn = lane & 15;
    const int m0 = blockIdx.x * 64;

    f4v acc[16];
#pragma unroll
    for (int n = 0; n < 16; ++n) acc[n] = (f4v){0.f, 0.f, 0.f, 0.f};

    for (int k0 = 0; k0 < 512; k0 += 32) {
        __syncthreads();
        {
            int r = tid & 63, c = (tid >> 6) * 8;
            const float* s = x + (size_t)(m0 + r) * 512 + k0 + c;
            float4v v0 = *(const float4v*)s, v1 = *(const float4v*)(s + 4);
            short hh[8], ll[8];
#pragma unroll
            for (int i = 0; i < 8; ++i) {
                float xv = (i < 4) ? v0[i] : v1[i - 4];
                u16 h = f2bf(xv);
                hh[i] = (short)h;
                ll[i] = (short)f2bf(xv - bf2f(h));
            }
            *(s8v*)&Ash[r][c] = (s8v){hh[0],hh[1],hh[2],hh[3],hh[4],hh[5],hh[6],hh[7]};
            *(s8v*)&Asl[r][c] = (s8v){ll[0],ll[1],ll[2],ll[3],ll[4],ll[5],ll[6],ll[7]};
        }
        __syncthreads();

        s8v ah = *(const s8v*)&Ash[w * 16 + qn][g * 8];
        s8v al = *(const s8v*)&Asl[w * 16 + qn][g * 8];
#pragma unroll
        for (int nt = 0; nt < 16; ++nt) {
            s8v bh = *(const s8v*)(Mth + (size_t)(nt * 16 + qn) * 512 + k0 + g * 8);
            s8v bl = *(const s8v*)(Mtl + (size_t)(nt * 16 + qn) * 512 + k0 + g * 8);
            acc[nt] = MF(ah, bh, acc[nt]);
            acc[nt] = MF(ah, bl, acc[nt]);
            acc[nt] = MF(al, bh, acc[nt]);
        }
    }

#pragma unroll
    for (int nt = 0; nt < 16; ++nt)
#pragma unroll
        for (int r = 0; r < 4; ++r) {
            int row = m0 + w * 16 + 4 * g + r;
            int col = nt * 16 + qn;
            q16[(size_t)row * 256 + col] = (_Float16)(acc[nt][r] + wv[col]);
        }
}

// ---------------------------------------------------------------------------
// Flash, split-KV: grid (LQ/64, B, 4). Per block: 64 q-rows, 512-key chunk.
// fp16 single-pass scores; fragments direct from global; no barriers.
// Writes unnormalized fp16 partial ctx + (m,l) per q-row.
__global__ __launch_bounds__(256, 3) void flash2(
    const _Float16* __restrict__ q16, const _Float16* __restrict__ y16,
    const _Float16* __restrict__ yTb, _Float16* __restrict__ part,
    float* __restrict__ ml)
{
    __shared__ _Float16 pls[4][16][40];
    const int tid = threadIdx.x;
    const int w = tid >> 6, lane = tid & 63;
    const int g = lane >> 4, qn = lane & 15;
    const int b = blockIdx.y, z = blockIdx.z;
    const int q0 = blockIdx.x * 64;
    const int qrow = q0 + w * 16 + qn;

    h8v qf[8];
    {
        const _Float16* qp = q16 + ((size_t)b * LQ + qrow) * F + g * 8;
#pragma unroll
        for (int s = 0; s < 8; ++s) qf[s] = *(const h8v*)(qp + s * 32);
    }
    f4v ctx[16];
#pragma unroll
    for (int n = 0; n < 16; ++n) ctx[n] = (f4v){0.f, 0.f, 0.f, 0.f};
    float m = -3.0e38f, l = 0.f;

    const _Float16* ya = y16 + ((size_t)b * LK + z * 512 + qn) * F + g * 8;
    const _Float16* yb = ya + 16 * F;
    const _Float16* vt = yTb + (((size_t)b * 64 + z * 16) * 256 + qn) * 32 + g * 8;

#pragma unroll 1
    for (int t = 0; t < 16; ++t) {
        f4v s0 = (f4v){0.f, 0.f, 0.f, 0.f}, s1 = (f4v){0.f, 0.f, 0.f, 0.f};
#pragma unroll
        for (int s = 0; s < 8; ++s) {
            h8v a0 = *(const h8v*)(ya + s * 32);
            h8v a1 = *(const h8v*)(yb + s * 32);
            s0 = MF16(a0, qf[s], s0);
            s1 = MF16(a1, qf[s], s1);
        }

        float vmax = fmaxf(fmaxf(fmaxf(s0[0], s0[1]), fmaxf(s0[2], s0[3])),
                           fmaxf(fmaxf(s1[0], s1[1]), fmaxf(s1[2], s1[3])));
        vmax = fmaxf(vmax, __shfl_xor(vmax, 16));
        vmax = fmaxf(vmax, __shfl_xor(vmax, 32));
        float mnew = fmaxf(m, vmax);
        float p0[4], p1[4], ps = 0.f;
#pragma unroll
        for (int r = 0; r < 4; ++r) {
            p0[r] = __expf(s0[r] - mnew);
            p1[r] = __expf(s1[r] - mnew);
            ps += p0[r] + p1[r];
        }
        ps += __shfl_xor(ps, 16);
        ps += __shfl_xor(ps, 32);

        if (!__all(vmax <= m)) {              // some q-row's max grew: rescale
            float alpha = __expf(m - mnew);   // ==1 for rows that didn't grow
            float a0_ = __shfl(alpha, 4 * g + 0);
            float a1_ = __shfl(alpha, 4 * g + 1);
            float a2_ = __shfl(alpha, 4 * g + 2);
            float a3_ = __shfl(alpha, 4 * g + 3);
            f4v av = (f4v){a0_, a1_, a2_, a3_};
#pragma unroll
            for (int n = 0; n < 16; ++n) ctx[n] *= av;
            l *= alpha;
        }
        m = mnew;
        l += ps;

        *(h4v*)&pls[w][qn][4 * g] =
            (h4v){(_Float16)p0[0], (_Float16)p0[1], (_Float16)p0[2], (_Float16)p0[3]};
        *(h4v*)&pls[w][qn][16 + 4 * g] =
            (h4v){(_Float16)p1[0], (_Float16)p1[1], (_Float16)p1[2], (_Float16)p1[3]};

        h8v pf = *(const h8v*)&pls[w][qn][g * 8];
#pragma unroll
        for (int nq = 0; nq < 4; ++nq) {
            const _Float16* vq = vt + nq * 2048;
#pragma unroll
            for (int nn = 0; nn < 4; ++nn) {
                h8v vf = *(const h8v*)(vq + nn * 512);
                ctx[nq * 4 + nn] = MF16(pf, vf, ctx[nq * 4 + nn]);
            }
        }
        ya += 32 * F;
        yb += 32 * F;
        vt += 8192;
    }

    size_t ibase = (size_t)b * LQ + q0 + w * 16;
    _Float16* pp = part + ((size_t)z * (BB * LQ) + ibase) * F;
#pragma unroll
    for (int n = 0; n < 16; ++n)
#pragma unroll
        for (int r = 0; r < 4; ++r)
            pp[(size_t)(4 * g + r) * F + n * 16 + qn] = (_Float16)ctx[n][r];
    if (g == 0) {
        size_t mi = (size_t)z * (BB * LQ) + ibase + qn;
        ml[2 * mi + 0] = m;
        ml[2 * mi + 1] = l;
    }
}

// ---------------------------------------------------------------------------
// out[i][e] = sum_f ctx[i][f] Nt[e][f] + cvec[e], where ctx is combined from
// the 4 split-KV partials during A-staging. fp16 single-pass MFMA.
__global__ __launch_bounds__(256) void gemm2c(
    const _Float16* __restrict__ part, const float* __restrict__ ml,
    const _Float16* __restrict__ Nt16, const float* __restrict__ cvec,
    float* __restrict__ out)
{
    __shared__ _Float16 Asb[64][40];
    __shared__ float scl[64][4];
    const int tid = threadIdx.x;
    const int w = tid >> 6, lane = tid & 63;
    const int g = lane >> 4, qn = lane & 15;
    const int wr = w >> 1, wc = w & 1;
    const int m0 = blockIdx.x * 64, e0 = blockIdx.y * 256;
    constexpr size_t PL = (size_t)BB * LQ * F;   // partial plane stride

    if (tid < 64) {
        size_t i = m0 + tid;
        float m0v = ml[2 * i], l0v = ml[2 * i + 1];
        float m1v = ml[2 * (PL / F + i)], l1v = ml[2 * (PL / F + i) + 1];
        float m2v = ml[2 * (2 * PL / F + i)], l2v = ml[2 * (2 * PL / F + i) + 1];
        float m3v = ml[2 * (3 * PL / F + i)], l3v = ml[2 * (3 * PL / F + i) + 1];
        float M = fmaxf(fmaxf(m0v, m1v), fmaxf(m2v, m3v));
        float e0v = __expf(m0v - M), e1v = __expf(m1v - M);
        float e2v = __expf(m2v - M), e3v = __expf(m3v - M);
        float inv = 1.f / (l0v * e0v + l1v * e1v + l2v * e2v + l3v * e3v);
        scl[tid][0] = e0v * inv;
        scl[tid][1] = e1v * inv;
        scl[tid][2] = e2v * inv;
        scl[tid][3] = e3v * inv;
    }

    f4v acc[2][8];
#pragma unroll
    for (int i = 0; i < 2; ++i)
#pragma unroll
        for (int j = 0; j < 8; ++j) acc[i][j] = (f4v){0.f, 0.f, 0.f, 0.f};

    for (int k0 = 0; k0 < F; k0 += 32) {
        __syncthreads();
        {
            int r = tid & 63, c = (tid >> 6) * 8;
            size_t base = (size_t)(m0 + r) * F + k0 + c;
            h8v p0 = *(const h8v*)(part + base);
            h8v p1 = *(const h8v*)(part + PL + base);
            h8v p2 = *(const h8v*)(part + 2 * PL + base);
            h8v p3 = *(const h8v*)(part + 3 * PL + base);
            float s0 = scl[r][0], s1 = scl[r][1], s2 = scl[r][2], s3 = scl[r][3];
#pragma unroll
            for (int i = 0; i < 8; ++i) {
                float v = (float)p0[i] * s0 + (float)p1[i] * s1 +
                          (float)p2[i] * s2 + (float)p3[i] * s3;
                Asb[r][c + i] = (_Float16)v;
            }
        }
        __syncthreads();

        h8v ah[2], bh[8];
#pragma unroll
        for (int mt = 0; mt < 2; ++mt)
            ah[mt] = *(const h8v*)&Asb[wr * 32 + mt * 16 + qn][g * 8];
#pragma unroll
        for (int nt = 0; nt < 8; ++nt)
            bh[nt] = *(const h8v*)(Nt16 + (size_t)(e0 + wc * 128 + nt * 16 + qn) * F + k0 + g * 8);
#pragma unroll
        for (int mt = 0; mt < 2; ++mt)
#pragma unroll
            for (int nt = 0; nt < 8; ++nt)
                acc[mt][nt] = MF16(ah[mt], bh[nt], acc[mt][nt]);
    }

#pragma unroll
    for (int mt = 0; mt < 2; ++mt)
#pragma unroll
        for (int nt = 0; nt < 8; ++nt)
#pragma unroll
            for (int r = 0; r < 4; ++r) {
                int gm = m0 + wr * 32 + mt * 16 + 4 * g + r;
                int gn = e0 + wc * 128 + nt * 16 + qn;
                out[(size_t)gm * E + gn] = acc[mt][nt][r] + cvec[gn];
            }
}

// ---------------------------------------------------------------------------
extern "C" void kernel_launch(void* const* d_in, const int* in_sizes, int n_in,
                              void* d_out, int out_size, void* d_ws, size_t ws_size,
                              hipStream_t stream)
{
    const float* x  = (const float*)d_in[0];   // [B,LQ,E]
    const float* y  = (const float*)d_in[1];   // [B,LK,F]
    const float* Wq = (const float*)d_in[2];
    const float* bq = (const float*)d_in[3];
    const float* Wk = (const float*)d_in[4];
    // d_in[5] = bk: per-row constant in scores -> softmax-invariant, unused.
    const float* Wv = (const float*)d_in[6];
    const float* bv = (const float*)d_in[7];
    const float* Wo = (const float*)d_in[8];
    const float* bo = (const float*)d_in[9];
    float* out = (float*)d_out;

    char* ws = (char*)d_ws;
    size_t off = 0;
    auto alloc = [&](size_t bytes) -> char* {
        char* p = ws + off;
        off = (off + bytes + 255) & ~(size_t)255;
        return p;
    };
    u16* Mth  = (u16*)alloc(sizeof(u16) * F * E);
    u16* Mtl  = (u16*)alloc(sizeof(u16) * F * E);
    float* wvec = (float*)alloc(sizeof(float) * F);
    float* cvec = (float*)alloc(sizeof(float) * E);
    u16* Nt16u = (u16*)alloc(sizeof(u16) * E * F);
    _Float16* q16 = (_Float16*)alloc(sizeof(u16) * (size_t)BB * LQ * F);
    _Float16* y16 = (_Float16*)alloc(sizeof(u16) * (size_t)BB * LK * F);
    _Float16* yTb = (_Float16*)alloc(sizeof(u16) * (size_t)BB * LK * F);
    _Float16* part = (_Float16*)alloc(sizeof(u16) * 4 * (size_t)BB * LQ * F);
    float* ml = (float*)alloc(sizeof(float) * 2 * 4 * (size_t)BB * LQ);
    (void)ws_size; (void)in_sizes; (void)n_in; (void)out_size;

    kvec_kernel<<<dim3(1), dim3(512), 0, stream>>>(Wk, bq, bv, Wo, bo, wvec, cvec);
    // Mt[f][e] = sum_a Wk[f][a] Wq[e][a] -> split bf16
    splitnt<0><<<dim3(F / 64, E / 256), dim3(256), 0, stream>>>(Wk, Wq, Mth, Mtl);
    // Nt[e][f] = sum_a Wo[a][e] Wv[f][a] -> fp16
    splitnt<2><<<dim3(E / 64, F / 256), dim3(256), 0, stream>>>(Wo, Wv, Nt16u, nullptr);
    prep16<<<dim3(LK / 64, BB), dim3(256), 0, stream>>>(y, y16, yTb);
    qprime16<<<dim3(BB * LQ / 64), dim3(256), 0, stream>>>(x, Mth, Mtl, wvec, q16);
    flash2<<<dim3(LQ / 64, BB, 4), dim3(256), 0, stream>>>(q16, y16, yTb, part, ml);
    gemm2c<<<dim3(BB * LQ / 64, E / 256), dim3(256), 0, stream>>>(
        part, ml, (const _Float16*)Nt16u, cvec, out);
}

// Round 3
// 229.400 us; speedup vs baseline: 2.0019x; 2.0019x over previous
//
#include <hip/hip_runtime.h>

// CrossAttentionModel on MI355X (gfx950) — round 3.
//
// Math (softmax row-constant invariance + sum(w)=1):
//   Mt[f][e] = sum_a Wk[f][a] Wq[e][a]   (split-bf16 3-pass, ~f32 accurate)
//   wvec[f]  = Wk bq ; cvec[e] = bv Wo + bo
//   q'[i][f] = sum_e x[i][e] Mt[f][e] + wvec[f]  (3-pass, stored fp16)
//   scores   = q' y^T   (fp16 32x32x16 MFMA)
//   out      = (softmax(scores) y) (Wv Wo) + cvec   (fp16 value path)
//
// R3: everything fragment-blocked. y is pre-transformed (prep16s) into
// MFMA-fragment-linear global arrays (yA for the score A-operand, yB for the
// PV B-operand) so flash staging is lane*16B-linear: coalesced global loads,
// conflict-free ds_write/ds_read. flash3: 1 block/CU, 8 waves x 32 q-rows,
// 32-key tiles, reg-staged single-buffer LDS with loads-in-flight-under-
// compute, split-KV=4, XCD-grouped block swizzle.

#define DEV static __device__ __forceinline__

typedef __attribute__((ext_vector_type(8))) short s8v;        // 8 bf16
typedef __attribute__((ext_vector_type(8))) _Float16 h8v;     // 8 fp16
typedef __attribute__((ext_vector_type(4))) _Float16 h4v;
typedef __attribute__((ext_vector_type(4))) float f4v;
typedef __attribute__((ext_vector_type(16))) float f16f;
typedef __attribute__((ext_vector_type(4))) float float4v;
typedef unsigned short u16;
typedef unsigned int u32;

constexpr int BB = 16;
constexpr int LQ = 1024;
constexpr int LK = 2048;
constexpr int E = 512;
constexpr int F = 256;
constexpr int AD = 512;

DEV u16 f2bf(float x) {
    u32 u = __builtin_bit_cast(u32, x);
    u += 0x7fff + ((u >> 16) & 1);
    return (u16)(u >> 16);
}
DEV float bf2f(u16 h) { return __builtin_bit_cast(float, (u32)h << 16); }

DEV f4v MF(s8v a, s8v b, f4v c) {
    return __builtin_amdgcn_mfma_f32_16x16x32_bf16(a, b, c, 0, 0, 0);
}
DEV f4v MF16(h8v a, h8v b, f4v c) {
    return __builtin_amdgcn_mfma_f32_16x16x32_f16(a, b, c, 0, 0, 0);
}
DEV f16f MF32(h8v a, h8v b, f16f c) {
    return __builtin_amdgcn_mfma_f32_32x32x16_f16(a, b, c, 0, 0, 0);
}

// ---------------------------------------------------------------------------
// wvec[o<256] = sum_a Wk[o][a] bq[a] ; cvec[e] = bo[e] + sum_a bv[a] Wo[a][e]
// one wave per output, wave-reduce.
__global__ __launch_bounds__(256) void kvec2(
    const float* __restrict__ Wk, const float* __restrict__ bq,
    const float* __restrict__ bv, const float* __restrict__ Wo,
    const float* __restrict__ bo, float* __restrict__ wvec,
    float* __restrict__ cvec)
{
    int o = blockIdx.x * 4 + (threadIdx.x >> 6);
    int lane = threadIdx.x & 63;
    float s = 0.f;
    if (o < F) {
        const float* r = Wk + (size_t)o * AD;
#pragma unroll
        for (int i = 0; i < 8; ++i) s += r[lane * 8 + i] * bq[lane * 8 + i];
    } else {
        int e = o - F;
#pragma unroll
        for (int i = 0; i < 8; ++i) {
            int a = lane * 8 + i;
            s += bv[a] * Wo[(size_t)a * E + e];
        }
    }
#pragma unroll
    for (int d = 1; d < 64; d <<= 1) s += __shfl_xor(s, d);
    if (lane == 0) {
        if (o < F) wvec[o] = s;
        else cvec[o - F] = bo[o - F] + s;
    }
}

// ---------------------------------------------------------------------------
// Split-bf16 NT GEMM (weights): C[m][n] = sum_k A[m][k]*B[n][k], K=512.
// MODE 0 (Mt): -> frag-blocked split bf16 (Oh hi, Ol lo) for qprime2 B-frags.
// MODE 2 (Nt): A read transposed; -> frag-blocked fp16 for gemm2c B-frags.
template <int MODE>
__global__ __launch_bounds__(256) void splitnt(
    const float* __restrict__ Ag, const float* __restrict__ Bg,
    u16* __restrict__ Oh, u16* __restrict__ Ol)
{
    __shared__ u16 Ash[64][40], Asl[64][40];
    __shared__ u16 Bsh[256][40], Bsl[256][40];

    const int tid = threadIdx.x;
    const int w = tid >> 6, lane = tid & 63;
    const int g = lane >> 4, qn = lane & 15;
    const int wr = w >> 1, wc = w & 1;
    const int m0 = blockIdx.x * 64, n0 = blockIdx.y * 256;

    f4v acc[2][8];
#pragma unroll
    for (int i = 0; i < 2; ++i)
#pragma unroll
        for (int j = 0; j < 8; ++j) acc[i][j] = (f4v){0.f, 0.f, 0.f, 0.f};

    for (int k0 = 0; k0 < 512; k0 += 32) {
        __syncthreads();
        if (MODE == 0) {
            int r = tid & 63, c = (tid >> 6) * 8;
            const float* s = Ag + (size_t)(m0 + r) * 512 + k0 + c;
            float4v v0 = *(const float4v*)s, v1 = *(const float4v*)(s + 4);
            short hh[8], ll[8];
#pragma unroll
            for (int i = 0; i < 8; ++i) {
                float x = (i < 4) ? v0[i] : v1[i - 4];
                u16 h = f2bf(x);
                hh[i] = (short)h;
                ll[i] = (short)f2bf(x - bf2f(h));
            }
            *(s8v*)&Ash[r][c] = (s8v){hh[0],hh[1],hh[2],hh[3],hh[4],hh[5],hh[6],hh[7]};
            *(s8v*)&Asl[r][c] = (s8v){ll[0],ll[1],ll[2],ll[3],ll[4],ll[5],ll[6],ll[7]};
        } else {
            int k = tid >> 3, mc = (tid & 7) * 8;
            const float* s = Ag + (size_t)(k0 + k) * 512 + m0 + mc;
            float4v v0 = *(const float4v*)s, v1 = *(const float4v*)(s + 4);
#pragma unroll
            for (int i = 0; i < 8; ++i) {
                float x = (i < 4) ? v0[i] : v1[i - 4];
                u16 h = f2bf(x);
                Ash[mc + i][k] = h;
                Asl[mc + i][k] = f2bf(x - bf2f(h));
            }
        }
        {
            const float* s = Bg + (size_t)(n0 + tid) * 512 + k0;
#pragma unroll
            for (int c = 0; c < 32; c += 8) {
                float4v v0 = *(const float4v*)(s + c), v1 = *(const float4v*)(s + c + 4);
                short hh[8], ll[8];
#pragma unroll
                for (int i = 0; i < 8; ++i) {
                    float x = (i < 4) ? v0[i] : v1[i - 4];
                    u16 h = f2bf(x);
                    hh[i] = (short)h;
                    ll[i] = (short)f2bf(x - bf2f(h));
                }
                *(s8v*)&Bsh[tid][c] = (s8v){hh[0],hh[1],hh[2],hh[3],hh[4],hh[5],hh[6],hh[7]};
                *(s8v*)&Bsl[tid][c] = (s8v){ll[0],ll[1],ll[2],ll[3],ll[4],ll[5],ll[6],ll[7]};
            }
        }
        __syncthreads();

        s8v ah[2], al[2], bh[8], bl[8];
#pragma unroll
        for (int mt = 0; mt < 2; ++mt) {
            ah[mt] = *(const s8v*)&Ash[wr * 32 + mt * 16 + qn][g * 8];
            al[mt] = *(const s8v*)&Asl[wr * 32 + mt * 16 + qn][g * 8];
        }
#pragma unroll
        for (int nt = 0; nt < 8; ++nt) {
            bh[nt] = *(const s8v*)&Bsh[wc * 128 + nt * 16 + qn][g * 8];
            bl[nt] = *(const s8v*)&Bsl[wc * 128 + nt * 16 + qn][g * 8];
        }
#pragma unroll
        for (int mt = 0; mt < 2; ++mt)
#pragma unroll
            for (int nt = 0; nt < 8; ++nt) {
                acc[mt][nt] = MF(ah[mt], bh[nt], acc[mt][nt]);
                acc[mt][nt] = MF(ah[mt], bl[nt], acc[mt][nt]);
                acc[mt][nt] = MF(al[mt], bh[nt], acc[mt][nt]);
            }
    }

#pragma unroll
    for (int mt = 0; mt < 2; ++mt)
#pragma unroll
        for (int nt = 0; nt < 8; ++nt)
#pragma unroll
            for (int r = 0; r < 4; ++r) {
                int gm = m0 + wr * 32 + mt * 16 + 4 * g + r;
                int gn = n0 + wc * 128 + nt * 16 + qn;
                float v = acc[mt][nt][r];
                if (MODE == 0) {
                    // blocked for qprime2 B-frag (16x16x32 bf16, m=f-row, n=e-col)
                    size_t off = (size_t)((gn >> 5) * 16 + (gm >> 4)) * 512 +
                                 (gm & 15) * 8 + ((gn >> 3) & 3) * 128 + (gn & 7);
                    u16 h = f2bf(v);
                    Oh[off] = h;
                    Ol[off] = f2bf(v - bf2f(h));
                } else {
                    // blocked for gemm2c B-frag (16x16x32 f16, m=e-row, n=f-col)
                    size_t off = (size_t)((gn >> 5) * 32 + (gm >> 4)) * 512 +
                                 (gm & 15) * 8 + ((gn >> 3) & 3) * 128 + (gn & 7);
                    Oh[off] = __builtin_bit_cast(u16, (_Float16)v);
                }
            }
}

// ---------------------------------------------------------------------------
// prep16s: y f32 -> fragment-blocked fp16 arrays for flash3.
// Per 32-key tile (16KB each):
//  yA (score A-op, A[32k x 16f] frags): byte = fs*1024 + hi*512 + k*16 + j*2,
//     element (k, f = fs*16 + hi*8 + j).
//  yB (PV B-op, B[16k x 32f] frags): byte = (ft*2+ks)*1024 + hi*512 + fl*16 + j*2,
//     element (k = ks*16 + hi*8 + j, f = ft*32 + fl).
__global__ __launch_bounds__(256) void prep16s(
    const float* __restrict__ y, _Float16* __restrict__ yA,
    _Float16* __restrict__ yB)
{
    __shared__ float Y[32][260];
    const int tid = threadIdx.x;
    const int b = blockIdx.y, t = blockIdx.x;
    const float* src = y + ((size_t)b * LK + t * 32) * F;
#pragma unroll
    for (int i = 0; i < 8; ++i) {
        int base = i * 1024 + tid * 4;
        int k = base >> 8, f = base & 255;
        *(float4v*)&Y[k][f] = *(const float4v*)(src + base);
    }
    __syncthreads();
    size_t tb = (size_t)(b * 64 + t) * 8192;
    // A-pass
#pragma unroll
    for (int i = 0; i < 4; ++i) {
        int c = i * 256 + tid;
        int k = c & 31, hi = (c >> 5) & 1, fs = c >> 6;
        int f0 = fs * 16 + hi * 8;
        float4v v0 = *(const float4v*)&Y[k][f0];
        float4v v1 = *(const float4v*)&Y[k][f0 + 4];
        h8v v;
#pragma unroll
        for (int j = 0; j < 4; ++j) { v[j] = (_Float16)v0[j]; v[4 + j] = (_Float16)v1[j]; }
        *(h8v*)(yA + tb + (size_t)c * 8) = v;
    }
    // B-pass
#pragma unroll
    for (int i = 0; i < 4; ++i) {
        int c = i * 256 + tid;
        int fl = c & 31, hi = (c >> 5) & 1, frag = c >> 6;
        int ft = frag >> 1, ks = frag & 1;
        int f = ft * 32 + fl, k0 = ks * 16 + hi * 8;
        h8v v;
#pragma unroll
        for (int j = 0; j < 8; ++j) v[j] = (_Float16)Y[k0 + j][f];
        *(h8v*)(yB + tb + (size_t)c * 8) = v;
    }
}

// ---------------------------------------------------------------------------
// q'[i][f] = sum_e x[i][e] Mt[f][e] + wvec[f] -> fp16.
// A (x rows) loaded per-lane direct + split; B from frag-blocked Mthb/Mtlb
// (coalesced 1KB frag loads, L1-hot).
__global__ __launch_bounds__(256) void qprime2(
    const float* __restrict__ x, const u16* __restrict__ Mthb,
    const u16* __restrict__ Mtlb, const float* __restrict__ wv,
    _Float16* __restrict__ q16)
{
    const int tid = threadIdx.x, w = tid >> 6, lane = tid & 63;
    const int g = lane >> 4, qn = lane & 15;
    const int m0 = blockIdx.x * 64;
    const int arow = m0 + w * 16 + qn;

    f4v acc[16];
#pragma unroll
    for (int n = 0; n < 16; ++n) acc[n] = (f4v){0.f, 0.f, 0.f, 0.f};

    for (int k0 = 0; k0 < 512; k0 += 32) {
        const float* xs = x + (size_t)arow * 512 + k0 + g * 8;
        float4v v0 = *(const float4v*)xs, v1 = *(const float4v*)(xs + 4);
        short hh[8], ll[8];
#pragma unroll
        for (int i = 0; i < 8; ++i) {
            float xv = (i < 4) ? v0[i] : v1[i - 4];
            u16 h = f2bf(xv);
            hh[i] = (short)h;
            ll[i] = (short)f2bf(xv - bf2f(h));
        }
        s8v ah = (s8v){hh[0],hh[1],hh[2],hh[3],hh[4],hh[5],hh[6],hh[7]};
        s8v al = (s8v){ll[0],ll[1],ll[2],ll[3],ll[4],ll[5],ll[6],ll[7]};
        int fb = (k0 >> 5) * 16;
#pragma unroll
        for (int nt = 0; nt < 16; ++nt) {
            s8v bh = *(const s8v*)(Mthb + (size_t)(fb + nt) * 512 + lane * 8);
            s8v bl = *(const s8v*)(Mtlb + (size_t)(fb + nt) * 512 + lane * 8);
            acc[nt] = MF(ah, bh, acc[nt]);
            acc[nt] = MF(ah, bl, acc[nt]);
            acc[nt] = MF(al, bh, acc[nt]);
        }
    }

#pragma unroll
    for (int nt = 0; nt < 16; ++nt)
#pragma unroll
        for (int r = 0; r < 4; ++r) {
            int row = m0 + w * 16 + 4 * g + r;
            int col = nt * 16 + qn;
            q16[(size_t)row * 256 + col] = (_Float16)(acc[nt][r] + wv[col]);
        }
}

// ---------------------------------------------------------------------------
// flash3: grid 256 flat -> (qb, b, z) XCD-grouped. 512 threads = 8 waves x
// 32 q-rows (256 q/block), 512-key chunk (16 tiles of 32), split-KV=4.
// 32x32x16 fp16 MFMA. Swapped scores S^T[32k][32q]: stats per-lane scalar.
// P through per-wave LDS in PV-A-frag layout. Reg-staged single-buffer tiles,
// next-next-tile loads in flight under compute.
__global__ __launch_bounds__(512) void flash3(
    const _Float16* __restrict__ q16, const _Float16* __restrict__ yA,
    const _Float16* __restrict__ yB, _Float16* __restrict__ part,
    float* __restrict__ ml)
{
    __shared__ _Float16 Asb[8192];      // y score-A frags (16KB)
    __shared__ _Float16 Bsb[8192];      // y PV-B frags (16KB)
    __shared__ _Float16 Pls[8][1024];   // per-wave P (2KB each)

    const int tid = threadIdx.x;
    const int w = tid >> 6, lane = tid & 63;
    const int q32 = lane & 31, hi = lane >> 5;

    int id = blockIdx.x;
    int xcd = id & 7, slot = id >> 3;
    int grp = xcd + 8 * (slot >> 2);    // 0..63  (b,z) group, same XCD class
    int qb = slot & 3;
    int b = grp >> 2, z = grp & 3;
    const int qw = qb * 256 + w * 32;

    // q fragments (B-operand): lane: q-col = q32, f-rows = s*16 + hi*8 + j
    h8v qf[16];
    {
        const _Float16* qp = q16 + ((size_t)b * LQ + qw + q32) * 256 + hi * 8;
#pragma unroll
        for (int s = 0; s < 16; ++s) qf[s] = *(const h8v*)(qp + s * 16);
    }
    f16f ctx[8];
#pragma unroll
    for (int i = 0; i < 8; ++i) ctx[i] = (f16f){};
    float mrun = -3.0e38f, lrun = 0.f;

    const size_t tbe = (size_t)(b * 64 + z * 16) * 8192;  // elem base of chunk
    h8v sA0, sA1, sB0, sB1;
    auto LD = [&](int t) {
        const h8v* pa = (const h8v*)(yA + tbe + (size_t)t * 8192);
        const h8v* pb = (const h8v*)(yB + tbe + (size_t)t * 8192);
        sA0 = pa[tid]; sA1 = pa[tid + 512];
        sB0 = pb[tid]; sB1 = pb[tid + 512];
    };
    auto ST = [&]() {
        ((h8v*)Asb)[tid] = sA0; ((h8v*)Asb)[tid + 512] = sA1;
        ((h8v*)Bsb)[tid] = sB0; ((h8v*)Bsb)[tid + 512] = sB1;
    };

    LD(0); ST(); LD(1);
    __syncthreads();

    for (int t = 0; t < 16; ++t) {
        // ---- scores: S^T[32k][32q], A = y frags, B = qf
        f16f S = (f16f){};
#pragma unroll
        for (int fs = 0; fs < 16; ++fs) {
            h8v a = *(const h8v*)(Asb + fs * 512 + lane * 8);
            S = MF32(a, qf[fs], S);
        }
        // ---- softmax (per-lane col q = q32)
        float mt = S[0];
#pragma unroll
        for (int r = 1; r < 16; ++r) mt = fmaxf(mt, S[r]);
        mt = fmaxf(mt, __shfl_xor(mt, 32));
        float mnew = fmaxf(mrun, mt);
        float p[16], ps = 0.f;
#pragma unroll
        for (int r = 0; r < 16; ++r) { p[r] = __expf(S[r] - mnew); ps += p[r]; }
        ps += __shfl_xor(ps, 32);
        if (!__all(mt <= mrun)) {
            float alpha = __expf(mrun - mnew);
            lrun = lrun * alpha + ps;
#pragma unroll
            for (int r = 0; r < 16; ++r) {
                int qr = (r & 3) + 8 * (r >> 2) + 4 * hi;
                float ar = __shfl(alpha, qr);
#pragma unroll
                for (int ft = 0; ft < 8; ++ft) ctx[ft][r] *= ar;
            }
        } else {
            lrun += ps;
        }
        mrun = mnew;
        // ---- P -> LDS (PV-frag layout): value (q32, k=(r&3)+8*(r>>2)+4*hi)
        {
            _Float16* pw = &Pls[w][0];
#pragma unroll
            for (int r2 = 0; r2 < 4; ++r2) {
                h4v pk = (h4v){(_Float16)p[4 * r2], (_Float16)p[4 * r2 + 1],
                               (_Float16)p[4 * r2 + 2], (_Float16)p[4 * r2 + 3]};
                *(h4v*)(pw + (r2 >> 1) * 512 + (r2 & 1) * 256 + q32 * 8 + hi * 4) = pk;
            }
        }
        // ---- PV: ctx[32q][32f per ft] += P[32q][32k] y[32k][32f]
#pragma unroll
        for (int ks = 0; ks < 2; ++ks) {
            h8v pa = *(const h8v*)(&Pls[w][ks * 512] + lane * 8);
#pragma unroll
            for (int ft = 0; ft < 8; ++ft) {
                h8v bf = *(const h8v*)(Bsb + (ft * 2 + ks) * 512 + lane * 8);
                ctx[ft] = MF32(pa, bf, ctx[ft]);
            }
        }
        // ---- staging rotation
        __syncthreads();
        if (t < 15) {
            ST();
            if (t < 14) LD(t + 2);
            __syncthreads();
        }
    }

    // ---- epilogue: unnormalized partials + (m, l)
    float linv = 1.f / lrun;
    _Float16* pp = part + ((size_t)z * (BB * LQ) + (size_t)b * LQ + qw) * 256;
#pragma unroll
    for (int r = 0; r < 16; ++r) {
        int qr = (r & 3) + 8 * (r >> 2) + 4 * hi;
        float ir = __shfl(linv, qr);
#pragma unroll
        for (int ft = 0; ft < 8; ++ft)
            pp[(size_t)qr * 256 + ft * 32 + q32] = (_Float16)(ctx[ft][r] * ir);
    }
    if (hi == 0) {
        size_t mi = (size_t)z * (BB * LQ) + (size_t)b * LQ + qw + q32;
        ml[2 * mi + 0] = mrun;
        ml[2 * mi + 1] = lrun;
    }
}

// ---------------------------------------------------------------------------
// out[i][e] = sum_f ctx[i][f] Nt[e][f] + cvec[e]; ctx combined from 4 split-KV
// partials during A-staging. B-frags from frag-blocked Ntb.
__global__ __launch_bounds__(256) void gemm2c(
    const _Float16* __restrict__ part, const float* __restrict__ ml,
    const u16* __restrict__ Ntb, const float* __restrict__ cvec,
    float* __restrict__ out)
{
    __shared__ _Float16 Asb[64][40];
    __shared__ float scl[64][4];
    const int tid = threadIdx.x;
    const int w = tid >> 6, lane = tid & 63;
    const int g = lane >> 4, qn = lane & 15;
    const int wr = w >> 1, wc = w & 1;
    const int m0 = blockIdx.x * 64, e0 = blockIdx.y * 256;
    constexpr size_t PL = (size_t)BB * LQ * F;
    constexpr size_t PR = (size_t)BB * LQ;

    if (tid < 64) {
        size_t i = m0 + tid;
        float m0v = ml[2 * i], l0v = ml[2 * i + 1];
        float m1v = ml[2 * (PR + i)], l1v = ml[2 * (PR + i) + 1];
        float m2v = ml[2 * (2 * PR + i)], l2v = ml[2 * (2 * PR + i) + 1];
        float m3v = ml[2 * (3 * PR + i)], l3v = ml[2 * (3 * PR + i) + 1];
        float M = fmaxf(fmaxf(m0v, m1v), fmaxf(m2v, m3v));
        float e0v = __expf(m0v - M), e1v = __expf(m1v - M);
        float e2v = __expf(m2v - M), e3v = __expf(m3v - M);
        // partials were already normalized by their own l; recombine weights:
        float inv = 1.f / (l0v * e0v + l1v * e1v + l2v * e2v + l3v * e3v);
        scl[tid][0] = l0v * e0v * inv;
        scl[tid][1] = l1v * e1v * inv;
        scl[tid][2] = l2v * e2v * inv;
        scl[tid][3] = l3v * e3v * inv;
    }

    f4v acc[2][8];
#pragma unroll
    for (int i = 0; i < 2; ++i)
#pragma unroll
        for (int j = 0; j < 8; ++j) acc[i][j] = (f4v){0.f, 0.f, 0.f, 0.f};

    for (int k0 = 0; k0 < F; k0 += 32) {
        __syncthreads();
        {
            int r = tid & 63, c = (tid >> 6) * 8;
            size_t base = (size_t)(m0 + r) * F + k0 + c;
            h8v p0 = *(const h8v*)(part + base);
            h8v p1 = *(const h8v*)(part + PL + base);
            h8v p2 = *(const h8v*)(part + 2 * PL + base);
            h8v p3 = *(const h8v*)(part + 3 * PL + base);
            float s0 = scl[r][0], s1 = scl[r][1], s2 = scl[r][2], s3 = scl[r][3];
#pragma unroll
            for (int i = 0; i < 8; ++i) {
                float v = (float)p0[i] * s0 + (float)p1[i] * s1 +
                          (float)p2[i] * s2 + (float)p3[i] * s3;
                Asb[r][c + i] = (_Float16)v;
            }
        }
        __syncthreads();

        h8v ah[2], bh[8];
#pragma unroll
        for (int mt = 0; mt < 2; ++mt)
            ah[mt] = *(const h8v*)&Asb[wr * 32 + mt * 16 + qn][g * 8];
        int eb = (e0 + wc * 128) >> 4;
#pragma unroll
        for (int nt = 0; nt < 8; ++nt)
            bh[nt] = *(const h8v*)((const _Float16*)Ntb +
                     (size_t)((k0 >> 5) * 32 + eb + nt) * 512 + lane * 8);
#pragma unroll
        for (int mt = 0; mt < 2; ++mt)
#pragma unroll
            for (int nt = 0; nt < 8; ++nt)
                acc[mt][nt] = MF16(ah[mt], bh[nt], acc[mt][nt]);
    }

#pragma unroll
    for (int mt = 0; mt < 2; ++mt)
#pragma unroll
        for (int nt = 0; nt < 8; ++nt)
#pragma unroll
            for (int r = 0; r < 4; ++r) {
                int gm = m0 + wr * 32 + mt * 16 + 4 * g + r;
                int gn = e0 + wc * 128 + nt * 16 + qn;
                out[(size_t)gm * E + gn] = acc[mt][nt][r] + cvec[gn];
            }
}

// ---------------------------------------------------------------------------
extern "C" void kernel_launch(void* const* d_in, const int* in_sizes, int n_in,
                              void* d_out, int out_size, void* d_ws, size_t ws_size,
                              hipStream_t stream)
{
    const float* x  = (const float*)d_in[0];   // [B,LQ,E]
    const float* y  = (const float*)d_in[1];   // [B,LK,F]
    const float* Wq = (const float*)d_in[2];
    const float* bq = (const float*)d_in[3];
    const float* Wk = (const float*)d_in[4];
    // d_in[5] = bk: per-row constant in scores -> softmax-invariant, unused.
    const float* Wv = (const float*)d_in[6];
    const float* bv = (const float*)d_in[7];
    const float* Wo = (const float*)d_in[8];
    const float* bo = (const float*)d_in[9];
    float* out = (float*)d_out;

    char* ws = (char*)d_ws;
    size_t off = 0;
    auto alloc = [&](size_t bytes) -> char* {
        char* p = ws + off;
        off = (off + bytes + 255) & ~(size_t)255;
        return p;
    };
    u16* Mthb = (u16*)alloc(sizeof(u16) * F * E);
    u16* Mtlb = (u16*)alloc(sizeof(u16) * F * E);
    float* wvec = (float*)alloc(sizeof(float) * F);
    float* cvec = (float*)alloc(sizeof(float) * E);
    u16* Ntb  = (u16*)alloc(sizeof(u16) * E * F);
    _Float16* q16 = (_Float16*)alloc(sizeof(u16) * (size_t)BB * LQ * F);
    _Float16* yA  = (_Float16*)alloc(sizeof(u16) * (size_t)BB * LK * F);
    _Float16* yB  = (_Float16*)alloc(sizeof(u16) * (size_t)BB * LK * F);
    _Float16* part = (_Float16*)alloc(sizeof(u16) * 4 * (size_t)BB * LQ * F);
    float* ml = (float*)alloc(sizeof(float) * 2 * 4 * (size_t)BB * LQ);
    (void)ws_size; (void)in_sizes; (void)n_in; (void)out_size;

    kvec2<<<dim3((F + E) / 4), dim3(256), 0, stream>>>(Wk, bq, bv, Wo, bo, wvec, cvec);
    splitnt<0><<<dim3(F / 64, E / 256), dim3(256), 0, stream>>>(Wk, Wq, Mthb, Mtlb);
    splitnt<2><<<dim3(E / 64, F / 256), dim3(256), 0, stream>>>(Wo, Wv, Ntb, nullptr);
    prep16s<<<dim3(LK / 32, BB), dim3(256), 0, stream>>>(y, yA, yB);
    qprime2<<<dim3(BB * LQ / 64), dim3(256), 0, stream>>>(x, Mthb, Mtlb, wvec, q16);
    flash3<<<dim3(256), dim3(512), 0, stream>>>(q16, yA, yB, part, ml);
    gemm2c<<<dim3(BB * LQ / 64, E / 256), dim3(256), 0, stream>>>(
        part, ml, Ntb, cvec, out);
}